// Round 1
// baseline (78.699 us; speedup 1.0000x reference)
//
#include <hip/hip_runtime.h>

#define NQ 4
#define DIM 16
#define NL 3
#define INV_4PI 0.07957747154594767f  // 1/(4*pi): rev = theta * INV_4PI -> sin(2*pi*rev) = sin(theta/2)

// ---- ring permutation, generated exactly as the reference composes it ----
__host__ __device__ constexpr int cnot_perm(int idx, int c, int t) {
    return idx ^ (((idx >> (3 - c)) & 1) << (3 - t));
}
__host__ __device__ constexpr int ring_idx(int j) {
    int v = j;
    // reference: total = ((arange[p0])[p1])[p2])[p3]  =>  RING[j] = p0(p1(p2(p3(j))))
    for (int c = 3; c >= 0; --c) v = cnot_perm(v, c, (c + 1) & 3);
    return v;
}

template <int Q>
__device__ __forceinline__ void apply_ry(float st[16], float c, float s) {
    constexpr int stride = 1 << (3 - Q);
    #pragma unroll
    for (int i = 0; i < 16; ++i) {
        if ((i & stride) == 0) {
            const int j = i | stride;
            const float s0 = st[i], s1 = st[j];
            st[i] = __builtin_fmaf(c, s0, -(s * s1));
            st[j] = __builtin_fmaf(c, s1, s * s0);
        }
    }
}

__device__ __forceinline__ void ring_perm(float st[16]) {
    constexpr int RP[16] = {
        ring_idx(0),  ring_idx(1),  ring_idx(2),  ring_idx(3),
        ring_idx(4),  ring_idx(5),  ring_idx(6),  ring_idx(7),
        ring_idx(8),  ring_idx(9),  ring_idx(10), ring_idx(11),
        ring_idx(12), ring_idx(13), ring_idx(14), ring_idx(15)};
    float t[16];
    #pragma unroll
    for (int i = 0; i < 16; ++i) t[i] = st[RP[i]];
    #pragma unroll
    for (int i = 0; i < 16; ++i) st[i] = t[i];
}

__global__ void __launch_bounds__(256)
qlayer_kernel(const float* __restrict__ x, const float* __restrict__ w,
              float* __restrict__ out, int B) {
    // ---- once-per-wave: all 24 weight sin/cos in ONE v_sin across lanes ----
    // lane k in [0,12): sin(w[k]/2); lane 12+k: cos(w[k]/2) = sin(w[k]/2 + pi/2)
    const int lane = threadIdx.x & 63;
    const int k = lane < 12 ? lane : (lane < 24 ? lane - 12 : 0);
    const float wk = w[k];
    const float rev = __builtin_fmaf(wk, INV_4PI, (lane >= 12) ? 0.25f : 0.0f);
    const int ti = __float_as_int(__builtin_amdgcn_sinf(rev));
    float cw[12], sw[12];
    #pragma unroll
    for (int kk = 0; kk < 12; ++kk) {
        sw[kk] = __int_as_float(__builtin_amdgcn_readlane(ti, kk));
        cw[kk] = __int_as_float(__builtin_amdgcn_readlane(ti, kk + 12));
    }

    const int b = blockIdx.x * blockDim.x + threadIdx.x;
    if (b >= B) return;

    // ---- input layer: product state from 4 per-batch angles ----
    const float4 xv = ((const float4*)x)[b];
    const float r0 = xv.x * INV_4PI, r1 = xv.y * INV_4PI;
    const float r2 = xv.z * INV_4PI, r3 = xv.w * INV_4PI;
    const float c0 = __builtin_amdgcn_cosf(r0), s0 = __builtin_amdgcn_sinf(r0);
    const float c1 = __builtin_amdgcn_cosf(r1), s1 = __builtin_amdgcn_sinf(r1);
    const float c2 = __builtin_amdgcn_cosf(r2), s2 = __builtin_amdgcn_sinf(r2);
    const float c3 = __builtin_amdgcn_cosf(r3), s3 = __builtin_amdgcn_sinf(r3);

    // qubit q <-> index bit (3-q); bit set => sin factor
    const float hi[4] = {c0 * c1, c0 * s1, s0 * c1, s0 * s1};  // bits (b3,b2)
    const float lo[4] = {c2 * c3, c2 * s3, s2 * c3, s2 * s3};  // bits (b1,b0)
    float st[16];
    #pragma unroll
    for (int i = 0; i < 16; ++i) st[i] = hi[i >> 2] * lo[i & 3];

    // ---- 3 layers of uniform-angle RYs + ring CNOT perm ----
    #pragma unroll
    for (int layer = 0; layer < NL; ++layer) {
        apply_ry<0>(st, cw[layer * 4 + 0], sw[layer * 4 + 0]);
        apply_ry<1>(st, cw[layer * 4 + 1], sw[layer * 4 + 1]);
        apply_ry<2>(st, cw[layer * 4 + 2], sw[layer * 4 + 2]);
        apply_ry<3>(st, cw[layer * 4 + 3], sw[layer * 4 + 3]);
        ring_perm(st);
    }

    // ---- probs + signed butterfly for the 4 PauliZ expectations ----
    float p[16];
    #pragma unroll
    for (int i = 0; i < 16; ++i) p[i] = st[i] * st[i];

    float a[8], o3 = 0.0f;
    #pragma unroll
    for (int kk = 0; kk < 8; ++kk) {
        a[kk] = p[2 * kk] + p[2 * kk + 1];
        o3 += p[2 * kk] - p[2 * kk + 1];
    }
    float e[4], o2 = 0.0f;
    #pragma unroll
    for (int m = 0; m < 4; ++m) {
        e[m] = a[2 * m] + a[2 * m + 1];
        o2 += a[2 * m] - a[2 * m + 1];
    }
    const float o1 = (e[0] - e[1]) + (e[2] - e[3]);
    const float o0 = (e[0] + e[1]) - (e[2] + e[3]);

    ((float4*)out)[b] = make_float4(o0, o1, o2, o3);
}

extern "C" void kernel_launch(void* const* d_in, const int* in_sizes, int n_in,
                              void* d_out, int out_size, void* d_ws, size_t ws_size,
                              hipStream_t stream) {
    const float* x = (const float*)d_in[0];
    const float* w = (const float*)d_in[1];
    float* out = (float*)d_out;
    const int B = in_sizes[0] / 4;
    const int block = 256;
    const int grid = (B + block - 1) / block;
    qlayer_kernel<<<grid, block, 0, stream>>>(x, w, out, B);
}

// Round 2
// 75.068 us; speedup vs baseline: 1.0484x; 1.0484x over previous
//
#include <hip/hip_runtime.h>

#define NQ 4
#define DIM 16
#define NL 3
#define INV_4PI 0.07957747154594767f  // rev = theta/(4*pi) -> sin(2*pi*rev) = sin(theta/2)

// Packed dual-FP32: lane processes TWO batch elements (A=.x, B=.y).
// gfx950 selects v_pk_fma_f32 / v_pk_mul_f32 / v_pk_add_f32 from <2 x float> IR.
typedef float v2f __attribute__((ext_vector_type(2)));

// ---- ring permutation, generated exactly as the reference composes it ----
__host__ __device__ constexpr int cnot_perm(int idx, int c, int t) {
    return idx ^ (((idx >> (3 - c)) & 1) << (3 - t));
}
__host__ __device__ constexpr int ring_idx(int j) {
    int v = j;
    for (int c = 3; c >= 0; --c) v = cnot_perm(v, c, (c + 1) & 3);
    return v;
}

template <int Q>
__device__ __forceinline__ void apply_ry(v2f st[16], float c, float s) {
    constexpr int stride = 1 << (3 - Q);
    const v2f cc = {c, c}, ss = {s, s};
    #pragma unroll
    for (int i = 0; i < 16; ++i) {
        if ((i & stride) == 0) {
            const int j = i | stride;
            const v2f s0 = st[i], s1 = st[j];
            st[i] = __builtin_elementwise_fma(cc, s0, -(ss * s1));  // pk_mul + pk_fma(neg)
            st[j] = __builtin_elementwise_fma(cc, s1, ss * s0);     // pk_mul + pk_fma
        }
    }
}

__device__ __forceinline__ void ring_perm(v2f st[16]) {
    constexpr int RP[16] = {
        ring_idx(0),  ring_idx(1),  ring_idx(2),  ring_idx(3),
        ring_idx(4),  ring_idx(5),  ring_idx(6),  ring_idx(7),
        ring_idx(8),  ring_idx(9),  ring_idx(10), ring_idx(11),
        ring_idx(12), ring_idx(13), ring_idx(14), ring_idx(15)};
    v2f t[16];
    #pragma unroll
    for (int i = 0; i < 16; ++i) t[i] = st[RP[i]];  // pure register renaming
    #pragma unroll
    for (int i = 0; i < 16; ++i) st[i] = t[i];
}

__global__ void __launch_bounds__(256)
qlayer_kernel(const float* __restrict__ x, const float* __restrict__ w,
              float* __restrict__ out, int B) {
    // ---- once-per-wave: all 24 weight sin/cos in ONE v_sin across lanes ----
    const int lane = threadIdx.x & 63;
    const int k = lane < 12 ? lane : (lane < 24 ? lane - 12 : 0);
    const float wk = w[k];
    const float rev = __builtin_fmaf(wk, INV_4PI, (lane >= 12) ? 0.25f : 0.0f);
    const int ti = __float_as_int(__builtin_amdgcn_sinf(rev));
    float cw[12], sw[12];
    #pragma unroll
    for (int kk = 0; kk < 12; ++kk) {
        sw[kk] = __int_as_float(__builtin_amdgcn_readlane(ti, kk));
        cw[kk] = __int_as_float(__builtin_amdgcn_readlane(ti, kk + 12));
    }

    const int half = B >> 1;
    const int t0i = blockIdx.x * blockDim.x + threadIdx.x;
    if (t0i >= half) return;
    const int bA = t0i;          // element A
    const int bB = t0i + half;   // element B  (both float4 accesses stay coalesced)

    // ---- input layer: product state, built packed {A,B} ----
    const float4 xA = ((const float4*)x)[bA];
    const float4 xB = ((const float4*)x)[bB];
    const float rA0 = xA.x * INV_4PI, rA1 = xA.y * INV_4PI, rA2 = xA.z * INV_4PI, rA3 = xA.w * INV_4PI;
    const float rB0 = xB.x * INV_4PI, rB1 = xB.y * INV_4PI, rB2 = xB.z * INV_4PI, rB3 = xB.w * INV_4PI;

    const v2f C0 = {__builtin_amdgcn_cosf(rA0), __builtin_amdgcn_cosf(rB0)};
    const v2f S0 = {__builtin_amdgcn_sinf(rA0), __builtin_amdgcn_sinf(rB0)};
    const v2f C1 = {__builtin_amdgcn_cosf(rA1), __builtin_amdgcn_cosf(rB1)};
    const v2f S1 = {__builtin_amdgcn_sinf(rA1), __builtin_amdgcn_sinf(rB1)};
    const v2f C2 = {__builtin_amdgcn_cosf(rA2), __builtin_amdgcn_cosf(rB2)};
    const v2f S2 = {__builtin_amdgcn_sinf(rA2), __builtin_amdgcn_sinf(rB2)};
    const v2f C3 = {__builtin_amdgcn_cosf(rA3), __builtin_amdgcn_cosf(rB3)};
    const v2f S3 = {__builtin_amdgcn_sinf(rA3), __builtin_amdgcn_sinf(rB3)};

    // qubit q <-> index bit (3-q); bit set => sin factor
    const v2f H[4] = {C0 * C1, C0 * S1, S0 * C1, S0 * S1};  // bits (b3,b2)
    const v2f L[4] = {C2 * C3, C2 * S3, S2 * C3, S2 * S3};  // bits (b1,b0)
    v2f st[16];
    #pragma unroll
    for (int i = 0; i < 16; ++i) st[i] = H[i >> 2] * L[i & 3];

    // ---- 3 layers of uniform-angle RYs + ring CNOT perm (SGPR-broadcast c,s) ----
    #pragma unroll
    for (int layer = 0; layer < NL; ++layer) {
        apply_ry<0>(st, cw[layer * 4 + 0], sw[layer * 4 + 0]);
        apply_ry<1>(st, cw[layer * 4 + 1], sw[layer * 4 + 1]);
        apply_ry<2>(st, cw[layer * 4 + 2], sw[layer * 4 + 2]);
        apply_ry<3>(st, cw[layer * 4 + 3], sw[layer * 4 + 3]);
        ring_perm(st);
    }

    // ---- probs + signed butterfly, all packed ----
    v2f p[16];
    #pragma unroll
    for (int i = 0; i < 16; ++i) p[i] = st[i] * st[i];

    v2f a[8], o3 = {0.0f, 0.0f};
    #pragma unroll
    for (int kk = 0; kk < 8; ++kk) {
        a[kk] = p[2 * kk] + p[2 * kk + 1];
        o3 += p[2 * kk] - p[2 * kk + 1];
    }
    v2f e[4], o2 = {0.0f, 0.0f};
    #pragma unroll
    for (int m = 0; m < 4; ++m) {
        e[m] = a[2 * m] + a[2 * m + 1];
        o2 += a[2 * m] - a[2 * m + 1];
    }
    const v2f o1 = (e[0] - e[1]) + (e[2] - e[3]);
    const v2f o0 = (e[0] + e[1]) - (e[2] + e[3]);

    ((float4*)out)[bA] = make_float4(o0.x, o1.x, o2.x, o3.x);
    ((float4*)out)[bB] = make_float4(o0.y, o1.y, o2.y, o3.y);
}

extern "C" void kernel_launch(void* const* d_in, const int* in_sizes, int n_in,
                              void* d_out, int out_size, void* d_ws, size_t ws_size,
                              hipStream_t stream) {
    const float* x = (const float*)d_in[0];
    const float* w = (const float*)d_in[1];
    float* out = (float*)d_out;
    const int B = in_sizes[0] / 4;
    const int half = B >> 1;
    const int block = 256;
    const int grid = (half + block - 1) / block;
    qlayer_kernel<<<grid, block, 0, stream>>>(x, w, out, B);
}